// Round 5
// baseline (722.932 us; speedup 1.0000x reference)
//
#include <hip/hip_runtime.h>

// Problem constants (match reference)
#define BB 4096
#define DD 16
#define MM 4
#define RR 2048
#define CC 10
#define TB 4            // batch rows per block
#define RPT (RR / 256)  // rules per thread = 8
#define REPS 5          // MEASUREMENT round: keep dispatch >42.6us poison fills.
                        // NEXT ROUND: set REPS=1 (final config).

typedef __attribute__((ext_vector_type(4))) float f32x4;
typedef __attribute__((ext_vector_type(2))) float f32x2;

// ---------------- prep kernel (unchanged) ----------------
__global__ __launch_bounds__(256) void prep_kernel(
    const float* __restrict__ cons, const int* __restrict__ rules,
    f32x2* __restrict__ wsumT2, unsigned int* __restrict__ codes)
{
    int gid = blockIdx.x * 256 + threadIdx.x;
    if (gid < RR * 5) {
        int r = gid / 5, c2 = gid - r * 5;
        const float* cr = cons + (size_t)r * (DD + 1) * CC + 2 * c2;
        float s0 = 0.0f, s1 = 0.0f;
#pragma unroll
        for (int j = 0; j < DD + 1; ++j) { s0 += cr[j * CC]; s1 += cr[j * CC + 1]; }
        f32x2 v; v.x = s0; v.y = s1;
        wsumT2[c2 * RR + r] = v;
    }
    if (gid < RR) {
        const int* rrp = rules + gid * DD;
        unsigned int code = 0;
#pragma unroll
        for (int g = 0; g < 4; ++g) {
            unsigned int byt = 0;
#pragma unroll
            for (int k = 0; k < 4; ++k)
                byt |= (((unsigned int)rrp[g * 4 + k]) & 3u) << (2 * k);
            code |= byt << (8 * g);
        }
        codes[gid] = code;
    }
}

// ---------------- main kernel ----------------
// Change vs R4: firing strengths p[8] (f32x4 over rows) are gathered ONCE in
// phase 2 (fully unrolled -> deep lgkmcnt pipeline) and kept in registers;
// phase 4 is pure stores + FMA (no re-gather). LDS gather count halved.
__global__ __launch_bounds__(256, 4) void anfis_main(
    const float* __restrict__ x, const float* __restrict__ centers,
    const float* __restrict__ widths, const f32x2* __restrict__ wsumT2,
    const unsigned int* __restrict__ codes,
    float* __restrict__ out, float* __restrict__ norm_fs, float* __restrict__ x_ext)
{
    // QUAD4 (16 KB) aliased with RED (10.9 KB): last QUAD4 read is in phase 2,
    // two block barriers (phase 3) separate it from RED writes in phase 5.
    __shared__ __align__(16) char pool[4 * 256 * sizeof(f32x4)];
    f32x4 (*QUAD4)[256] = (f32x4 (*)[256])pool;  // [g][e] -> rows
    float (*RED)[68]    = (float (*)[68])pool;   // [40][64+pad]

    __shared__ float MF[TB][64];
    __shared__ f32x4 PAIR4[8][16];
    __shared__ float xs[TB][DD];
    __shared__ float sx[TB];
    __shared__ float wpart[4][TB];
    __shared__ float invl[TB];
    __shared__ float oscale[TB];
    __shared__ float part2[TB * CC][4];

    const int tid = threadIdx.x;
    const int b0 = blockIdx.x * TB;
    const int lane = tid & 63;
    const int wv = tid >> 6;

    // ---- phase 1a: load x rows, emit x_ext (once) ----
    if (tid < TB * DD) {
        int row = tid / DD, d = tid % DD;
        float v = x[(b0 + row) * DD + d];
        xs[row][d] = v;
        x_ext[(b0 + row) * (DD + 1) + d] = v;
    }
    if (tid < TB) x_ext[(b0 + tid) * (DD + 1) + DD] = 1.0f;
    __syncthreads();
    if (tid < TB) {
        float s = 1.0f;
#pragma unroll
        for (int d = 0; d < DD; ++d) s += xs[tid][d];
        sx[tid] = s;
    }

#pragma unroll 1
    for (int rep = 0; rep < REPS; ++rep) {
        __syncthreads();  // prior-rep RED/part2 reads done before pool rewrite

        // ---- phase 1b: membership values ----
        {
            int row = tid >> 6, dm = tid & 63, d = dm >> 2, m = dm & 3;
            float c = centers[d * MM + m];
            float w = widths[d * MM + m];
            float z = xs[row][d] - c;
            MF[row][dm] = expf(-(z * z) / (2.0f * w * w));
        }
        __syncthreads();

        // ---- phase 1c: pair tables, row-interleaved ----
        if (tid < 8 * 16) {
            int p = tid >> 4, e = tid & 15;
            int i0 = e & 3, i1 = e >> 2;
            f32x4 v;
#pragma unroll
            for (int row = 0; row < TB; ++row)
                v[row] = MF[row][(2 * p) * 4 + i0] * MF[row][(2 * p + 1) * 4 + i1];
            PAIR4[p][e] = v;
        }
        __syncthreads();

        // ---- phase 1d: quad tables, row-interleaved ----
#pragma unroll
        for (int i = tid; i < 4 * 256; i += 256) {
            int g = i >> 8, e = i & 255;
            QUAD4[g][e] = PAIR4[2 * g][e & 15] * PAIR4[2 * g + 1][e >> 4];
        }
        __syncthreads();

        // ---- phase 2: gather firing strengths ONCE, keep in registers ----
        unsigned int creg[RPT];
#pragma unroll
        for (int j = 0; j < RPT; ++j) creg[j] = codes[tid + 256 * j];

        f32x4 p[RPT];
#pragma unroll
        for (int j = 0; j < RPT; ++j) {
            unsigned int code = creg[j];
            f32x4 q0 = QUAD4[0][code & 255u];
            f32x4 q1 = QUAD4[1][(code >> 8) & 255u];
            f32x4 q2 = QUAD4[2][(code >> 16) & 255u];
            f32x4 q3 = QUAD4[3][code >> 24];
            p[j] = (q0 * q1) * (q2 * q3);
        }

        // ---- phase 3: per-row fs total across block ----
        float ssum[TB];
#pragma unroll
        for (int row = 0; row < TB; ++row) {
            float s = 0.0f;
#pragma unroll
            for (int j = 0; j < RPT; ++j) s += p[j][row];
            ssum[row] = s;
        }
#pragma unroll
        for (int row = 0; row < TB; ++row) {
            float s = ssum[row];
#pragma unroll
            for (int off = 32; off > 0; off >>= 1) s += __shfl_xor(s, off, 64);
            if (lane == 0) wpart[wv][row] = s;
        }
        __syncthreads();
        if (tid < TB) {
            float t = wpart[0][tid] + wpart[1][tid] + wpart[2][tid] + wpart[3][tid];
            float inv = 1.0f / (t + 1e-9f);
            invl[tid] = inv;
            oscale[tid] = sx[tid] * inv;
        }
        __syncthreads();

        const float inv0 = invl[0], inv1 = invl[1], inv2 = invl[2], inv3 = invl[3];

        // ---- phase 4: stores + FMA from registers (no LDS) ----
        float acc[TB][CC];
#pragma unroll
        for (int row = 0; row < TB; ++row)
#pragma unroll
            for (int c = 0; c < CC; ++c) acc[row][c] = 0.0f;

#pragma unroll
        for (int j = 0; j < RPT; ++j) {
            int r = tid + 256 * j;
            norm_fs[(size_t)(b0 + 0) * RR + r] = p[j][0] * inv0;
            norm_fs[(size_t)(b0 + 1) * RR + r] = p[j][1] * inv1;
            norm_fs[(size_t)(b0 + 2) * RR + r] = p[j][2] * inv2;
            norm_fs[(size_t)(b0 + 3) * RR + r] = p[j][3] * inv3;

            f32x2 w01 = wsumT2[0 * RR + r];
            f32x2 w23 = wsumT2[1 * RR + r];
            f32x2 w45 = wsumT2[2 * RR + r];
            f32x2 w67 = wsumT2[3 * RR + r];
            f32x2 w89 = wsumT2[4 * RR + r];
            float wc[CC] = {w01.x, w01.y, w23.x, w23.y, w45.x,
                            w45.y, w67.x, w67.y, w89.x, w89.y};
#pragma unroll
            for (int row = 0; row < TB; ++row)
#pragma unroll
                for (int c = 0; c < CC; ++c)
                    acc[row][c] = fmaf(p[j][row], wc[c], acc[row][c]);
        }

        // ---- phase 5: reduce acc across block (RED aliases dead QUAD4) ----
#pragma unroll
        for (int row = 0; row < TB; ++row) {
#pragma unroll
            for (int c = 0; c < CC; ++c) {
                float s = acc[row][c];
                s += __shfl_xor(s, 1, 64);
                s += __shfl_xor(s, 2, 64);
                if ((lane & 3) == 0) RED[row * CC + c][wv * 16 + (lane >> 2)] = s;
            }
        }
        __syncthreads();
        if (tid < 160) {
            int v = tid % 40, ch = tid / 40;
            float s = 0.0f;
            int base = ch * 16;
#pragma unroll
            for (int i = 0; i < 16; ++i) s += RED[v][base + i];
            part2[v][ch] = s;
        }
        __syncthreads();
        if (tid < TB * CC) {
            float val = part2[tid][0] + part2[tid][1] + part2[tid][2] + part2[tid][3];
            int row = tid / CC, c = tid % CC;
            out[(b0 + row) * CC + c] = oscale[row] * val;
        }
    }
}

// ---------------- launch ----------------
extern "C" void kernel_launch(void* const* d_in, const int* in_sizes, int n_in,
                              void* d_out, int out_size, void* d_ws, size_t ws_size,
                              hipStream_t stream) {
    const float* x       = (const float*)d_in[0];
    const float* centers = (const float*)d_in[1];
    const float* widths  = (const float*)d_in[2];
    const float* cons    = (const float*)d_in[3];
    const int*   rules   = (const int*)d_in[4];

    float* out_p     = (float*)d_out;                       // (B, C)
    float* norm_fs_p = out_p + (size_t)BB * CC;             // (B, R)
    float* x_ext_p   = norm_fs_p + (size_t)BB * RR;         // (B, D+1)

    f32x2* wsumT2 = (f32x2*)d_ws;                           // 5*2048 float2 = 80 KB
    unsigned int* codes = (unsigned int*)((char*)d_ws + (size_t)5 * RR * sizeof(f32x2));

    prep_kernel<<<(RR * 5 + 255) / 256, 256, 0, stream>>>(cons, rules, wsumT2, codes);
    anfis_main<<<BB / TB, 256, 0, stream>>>(x, centers, widths, wsumT2, codes,
                                            out_p, norm_fs_p, x_ext_p);
}

// Round 7
// 668.557 us; speedup vs baseline: 1.0813x; 1.0813x over previous
//
#include <hip/hip_runtime.h>

// Problem constants (match reference)
#define BB 4096
#define DD 16
#define MM 4
#define RR 2048
#define CC 10
#define TB 4            // batch rows per block
#define RPT (RR / 256)  // rules per thread = 8
#define REPS 5          // MEASUREMENT round (verify spill fix in counters).
                        // NEXT ROUND: REPS=1 final config.

typedef __attribute__((ext_vector_type(4))) float f32x4;
typedef __attribute__((ext_vector_type(2))) float f32x2;

// ---------------- prep kernel (unchanged) ----------------
__global__ __launch_bounds__(256) void prep_kernel(
    const float* __restrict__ cons, const int* __restrict__ rules,
    f32x2* __restrict__ wsumT2, unsigned int* __restrict__ codes)
{
    int gid = blockIdx.x * 256 + threadIdx.x;
    if (gid < RR * 5) {
        int r = gid / 5, c2 = gid - r * 5;
        const float* cr = cons + (size_t)r * (DD + 1) * CC + 2 * c2;
        float s0 = 0.0f, s1 = 0.0f;
#pragma unroll
        for (int j = 0; j < DD + 1; ++j) { s0 += cr[j * CC]; s1 += cr[j * CC + 1]; }
        f32x2 v; v.x = s0; v.y = s1;
        wsumT2[c2 * RR + r] = v;
    }
    if (gid < RR) {
        const int* rrp = rules + gid * DD;
        unsigned int code = 0;
#pragma unroll
        for (int g = 0; g < 4; ++g) {
            unsigned int byt = 0;
#pragma unroll
            for (int k = 0; k < 4; ++k)
                byt |= (((unsigned int)rrp[g * 4 + k]) & 3u) << (2 * k);
            code |= byt << (8 * g);
        }
        codes[gid] = code;
    }
}

// ---------------- main kernel ----------------
// Single-pass structure (gather fs once) with SPILL-PROOF codegen: firing
// strengths live in NAMED f32x4 vars p0..p7 (no runtime-indexable array ->
// backend cannot demote to scratch; R5's f32x4 p[8] array went to scratch:
// FETCH 537KB -> 1.07GB, per-rep 17.8 -> 130us).
__global__ __launch_bounds__(256, 4) void anfis_main(
    const float* __restrict__ x, const float* __restrict__ centers,
    const float* __restrict__ widths, const f32x2* __restrict__ wsumT2,
    const unsigned int* __restrict__ codes,
    float* __restrict__ out, float* __restrict__ norm_fs, float* __restrict__ x_ext)
{
    // QUAD4 (16 KB) aliased with RED (10.9 KB): last QUAD4 read (gathers) is
    // separated from first RED write by the phase-3 barriers.
    __shared__ __align__(16) char pool[4 * 256 * sizeof(f32x4)];
    f32x4 (*QUAD4)[256] = (f32x4 (*)[256])pool;  // [g][e] -> rows
    float (*RED)[68]    = (float (*)[68])pool;   // [40][64+pad]

    __shared__ float MF[TB][64];
    __shared__ f32x4 PAIR4[8][16];
    __shared__ float xs[TB][DD];
    __shared__ float sx[TB];
    __shared__ float wpart[4][TB];
    __shared__ float invl[TB];
    __shared__ float oscale[TB];
    __shared__ float part2[TB * CC][4];

    const int tid = threadIdx.x;
    const int b0 = blockIdx.x * TB;
    const int lane = tid & 63;
    const int wv = tid >> 6;

    // ---- phase 1a: load x rows, emit x_ext (once) ----
    if (tid < TB * DD) {
        int row = tid / DD, d = tid % DD;
        float v = x[(b0 + row) * DD + d];
        xs[row][d] = v;
        x_ext[(b0 + row) * (DD + 1) + d] = v;
    }
    if (tid < TB) x_ext[(b0 + tid) * (DD + 1) + DD] = 1.0f;
    __syncthreads();
    if (tid < TB) {
        float s = 1.0f;
#pragma unroll
        for (int d = 0; d < DD; ++d) s += xs[tid][d];
        sx[tid] = s;
    }

#pragma unroll 1
    for (int rep = 0; rep < REPS; ++rep) {
        __syncthreads();  // prior-rep part2/RED reads done before pool rewrite

        // ---- phase 1b: membership values ----
        {
            int row = tid >> 6, dm = tid & 63, d = dm >> 2, m = dm & 3;
            float c = centers[d * MM + m];
            float w = widths[d * MM + m];
            float z = xs[row][d] - c;
            MF[row][dm] = expf(-(z * z) / (2.0f * w * w));
        }
        __syncthreads();

        // ---- phase 1c: pair tables, row-interleaved ----
        if (tid < 8 * 16) {
            int p = tid >> 4, e = tid & 15;
            int i0 = e & 3, i1 = e >> 2;
            f32x4 v;
#pragma unroll
            for (int row = 0; row < TB; ++row)
                v[row] = MF[row][(2 * p) * 4 + i0] * MF[row][(2 * p + 1) * 4 + i1];
            PAIR4[p][e] = v;
        }
        __syncthreads();

        // ---- phase 1d: quad tables, row-interleaved ----
#pragma unroll
        for (int i = tid; i < 4 * 256; i += 256) {
            int g = i >> 8, e = i & 255;
            QUAD4[g][e] = PAIR4[2 * g][e & 15] * PAIR4[2 * g + 1][e >> 4];
        }
        __syncthreads();

        // ---- phase 2: gather firing strengths ONCE into NAMED registers ----
        const unsigned int cr0 = codes[tid];
        const unsigned int cr1 = codes[tid + 256];
        const unsigned int cr2 = codes[tid + 512];
        const unsigned int cr3 = codes[tid + 768];
        const unsigned int cr4 = codes[tid + 1024];
        const unsigned int cr5 = codes[tid + 1280];
        const unsigned int cr6 = codes[tid + 1536];
        const unsigned int cr7 = codes[tid + 1792];

        f32x4 p0, p1, p2, p3, p4, p5, p6, p7;
#define GATHER(PJ, CODE) { \
        f32x4 q0 = QUAD4[0][(CODE) & 255u]; \
        f32x4 q1 = QUAD4[1][((CODE) >> 8) & 255u]; \
        f32x4 q2 = QUAD4[2][((CODE) >> 16) & 255u]; \
        f32x4 q3 = QUAD4[3][(CODE) >> 24]; \
        PJ = (q0 * q1) * (q2 * q3); }
        GATHER(p0, cr0) GATHER(p1, cr1) GATHER(p2, cr2) GATHER(p3, cr3)
        GATHER(p4, cr4) GATHER(p5, cr5) GATHER(p6, cr6) GATHER(p7, cr7)
#undef GATHER

        // ---- phase 3: per-row fs total across block ----
        const f32x4 psum = ((p0 + p1) + (p2 + p3)) + ((p4 + p5) + (p6 + p7));
#pragma unroll
        for (int row = 0; row < TB; ++row) {
            float s = psum[row];
#pragma unroll
            for (int off = 32; off > 0; off >>= 1) s += __shfl_xor(s, off, 64);
            if (lane == 0) wpart[wv][row] = s;
        }
        __syncthreads();
        if (tid < TB) {
            float t = wpart[0][tid] + wpart[1][tid] + wpart[2][tid] + wpart[3][tid];
            float inv = 1.0f / (t + 1e-9f);
            invl[tid] = inv;
            oscale[tid] = sx[tid] * inv;
        }
        __syncthreads();

        const float inv0 = invl[0], inv1 = invl[1], inv2 = invl[2], inv3 = invl[3];

        // ---- phase 4: stores + FMA from named registers (no LDS) ----
        float acc[TB][CC];
#pragma unroll
        for (int row = 0; row < TB; ++row)
#pragma unroll
            for (int c = 0; c < CC; ++c) acc[row][c] = 0.0f;

#define PHASE4(PJ, J) { \
        const int r = tid + 256 * (J); \
        norm_fs[(size_t)(b0 + 0) * RR + r] = PJ[0] * inv0; \
        norm_fs[(size_t)(b0 + 1) * RR + r] = PJ[1] * inv1; \
        norm_fs[(size_t)(b0 + 2) * RR + r] = PJ[2] * inv2; \
        norm_fs[(size_t)(b0 + 3) * RR + r] = PJ[3] * inv3; \
        const f32x2 w01 = wsumT2[0 * RR + r]; \
        const f32x2 w23 = wsumT2[1 * RR + r]; \
        const f32x2 w45 = wsumT2[2 * RR + r]; \
        const f32x2 w67 = wsumT2[3 * RR + r]; \
        const f32x2 w89 = wsumT2[4 * RR + r]; \
        const float wc[CC] = {w01.x, w01.y, w23.x, w23.y, w45.x, \
                              w45.y, w67.x, w67.y, w89.x, w89.y}; \
        _Pragma("unroll") \
        for (int row = 0; row < TB; ++row) { \
            _Pragma("unroll") \
            for (int c = 0; c < CC; ++c) \
                acc[row][c] = fmaf(PJ[row], wc[c], acc[row][c]); \
        } }
        PHASE4(p0, 0) PHASE4(p1, 1) PHASE4(p2, 2) PHASE4(p3, 3)
        PHASE4(p4, 4) PHASE4(p5, 5) PHASE4(p6, 6) PHASE4(p7, 7)
#undef PHASE4

        // ---- phase 5: reduce acc across block (RED aliases dead QUAD4) ----
#pragma unroll
        for (int row = 0; row < TB; ++row) {
#pragma unroll
            for (int c = 0; c < CC; ++c) {
                float s = acc[row][c];
                s += __shfl_xor(s, 1, 64);
                s += __shfl_xor(s, 2, 64);
                if ((lane & 3) == 0) RED[row * CC + c][wv * 16 + (lane >> 2)] = s;
            }
        }
        __syncthreads();
        if (tid < 160) {
            int v = tid % 40, ch = tid / 40;
            float s = 0.0f;
            int base = ch * 16;
#pragma unroll
            for (int i = 0; i < 16; ++i) s += RED[v][base + i];
            part2[v][ch] = s;
        }
        __syncthreads();
        if (tid < TB * CC) {
            float val = part2[tid][0] + part2[tid][1] + part2[tid][2] + part2[tid][3];
            int row = tid / CC, c = tid % CC;
            out[(b0 + row) * CC + c] = oscale[row] * val;
        }
    }
}

// ---------------- launch ----------------
extern "C" void kernel_launch(void* const* d_in, const int* in_sizes, int n_in,
                              void* d_out, int out_size, void* d_ws, size_t ws_size,
                              hipStream_t stream) {
    const float* x       = (const float*)d_in[0];
    const float* centers = (const float*)d_in[1];
    const float* widths  = (const float*)d_in[2];
    const float* cons    = (const float*)d_in[3];
    const int*   rules   = (const int*)d_in[4];

    float* out_p     = (float*)d_out;                       // (B, C)
    float* norm_fs_p = out_p + (size_t)BB * CC;             // (B, R)
    float* x_ext_p   = norm_fs_p + (size_t)BB * RR;         // (B, D+1)

    f32x2* wsumT2 = (f32x2*)d_ws;                           // 5*2048 float2 = 80 KB
    unsigned int* codes = (unsigned int*)((char*)d_ws + (size_t)5 * RR * sizeof(f32x2));

    prep_kernel<<<(RR * 5 + 255) / 256, 256, 0, stream>>>(cons, rules, wsumT2, codes);
    anfis_main<<<BB / TB, 256, 0, stream>>>(x, centers, widths, wsumT2, codes,
                                            out_p, norm_fs_p, x_ext_p);
}

// Round 8
// 89.551 us; speedup vs baseline: 8.0728x; 7.4656x over previous
//
#include <hip/hip_runtime.h>

// Problem constants (match reference)
#define BB 4096
#define DD 16
#define MM 4
#define RR 2048
#define CC 10
#define TB 2            // batch rows per block -> grid 2048 = 8 blocks/CU (100% occ)
#define RPT (RR / 256)  // rules per thread = 8

typedef __attribute__((ext_vector_type(4))) float f32x4;
typedef __attribute__((ext_vector_type(2))) float f32x2;

// ---------------- prep kernel ----------------
// wsum packed as 3 coalesced streams: wsum4a[r]=c0..3, wsum4b[r]=c4..7,
// wsum2[r]=c8..9.  codes[r] = packed 2-bit indices, byte g = dims 4g..4g+3.
__global__ __launch_bounds__(256) void prep_kernel(
    const float* __restrict__ cons, const int* __restrict__ rules,
    float* __restrict__ wsum4a, float* __restrict__ wsum4b,
    float* __restrict__ wsum2, unsigned int* __restrict__ codes)
{
    int gid = blockIdx.x * 256 + threadIdx.x;
    if (gid < RR * CC) {
        int r = gid / CC, c = gid - r * CC;
        const float* cr = cons + (size_t)r * (DD + 1) * CC + c;
        float s = 0.0f;
#pragma unroll
        for (int j = 0; j < DD + 1; ++j) s += cr[j * CC];
        if (c < 4)      wsum4a[r * 4 + c] = s;
        else if (c < 8) wsum4b[r * 4 + (c - 4)] = s;
        else            wsum2[r * 2 + (c - 8)] = s;
    }
    if (gid < RR) {
        const int* rrp = rules + gid * DD;
        unsigned int code = 0;
#pragma unroll
        for (int g = 0; g < 4; ++g) {
            unsigned int byt = 0;
#pragma unroll
            for (int k = 0; k < 4; ++k)
                byt |= (((unsigned int)rrp[g * 4 + k]) & 3u) << (2 * k);
            code |= byt << (8 * g);
        }
        codes[gid] = code;
    }
}

// ---------------- main kernel ----------------
// R4's PROVEN two-pass structure (unroll-1 rule loops, small live sets, no
// spill at 56 VGPR) with TB=2: grid 2048 -> 8 blocks/CU -> 100% occupancy
// (launch_bounds(256,8) caps VGPR at 64; acc is only 20 regs now), and f32x2
// quad tables -> ds_read_b64 random gathers (~4-way bank conflicts ~= free)
// instead of b128 (~8-way).
__global__ __launch_bounds__(256, 8) void anfis_main(
    const float* __restrict__ x, const float* __restrict__ centers,
    const float* __restrict__ widths, const f32x4* __restrict__ wsum4a,
    const f32x4* __restrict__ wsum4b, const f32x2* __restrict__ wsum2,
    const unsigned int* __restrict__ codes,
    float* __restrict__ out, float* __restrict__ norm_fs, float* __restrict__ x_ext)
{
    // Q2 (8 KB) aliased with RED (5.4 KB): last Q2 read (phase-4 gathers) is
    // barrier-separated from RED writes (phase 5).
    __shared__ __align__(16) char pool[4 * 256 * sizeof(f32x2)];
    f32x2 (*Q2)[256] = (f32x2 (*)[256])pool;   // [g][e] -> 2 rows
    float (*RED)[68] = (float (*)[68])pool;    // [20][64+pad]

    __shared__ float MF[TB][64];     // [row][d*4+m]
    __shared__ f32x2 PAIR2[8][16];   // [p][i0+4*i1] -> 2 rows
    __shared__ float xs[TB][DD];
    __shared__ float sx[TB];
    __shared__ float wpart[4][TB];
    __shared__ float invl[TB];
    __shared__ float oscale[TB];
    __shared__ float part2[TB * CC][4];

    const int tid = threadIdx.x;
    const int b0 = blockIdx.x * TB;
    const int lane = tid & 63;
    const int wv = tid >> 6;

    // ---- phase 1a: load x rows, emit x_ext ----
    if (tid < TB * (DD + 1)) {
        int row = tid / (DD + 1), col = tid % (DD + 1);
        float v = (col < DD) ? x[(b0 + row) * DD + col] : 1.0f;
        if (col < DD) xs[row][col] = v;
        x_ext[(b0 + row) * (DD + 1) + col] = v;
    }
    __syncthreads();
    if (tid < TB) {
        float s = 1.0f;
#pragma unroll
        for (int d = 0; d < DD; ++d) s += xs[tid][d];
        sx[tid] = s;
    }

    // ---- phase 1b: membership values (2 rows x 64) ----
    if (tid < TB * 64) {
        int row = tid >> 6, dm = tid & 63, d = dm >> 2, m = dm & 3;
        float c = centers[d * MM + m];
        float w = widths[d * MM + m];
        float z = xs[row][d] - c;
        MF[row][dm] = expf(-(z * z) / (2.0f * w * w));
    }
    __syncthreads();

    // ---- phase 1c: pair tables, row-interleaved (f32x2) ----
    if (tid < 8 * 16) {
        int p = tid >> 4, e = tid & 15;
        int i0 = e & 3, i1 = e >> 2;
        f32x2 v;
        v.x = MF[0][(2 * p) * 4 + i0] * MF[0][(2 * p + 1) * 4 + i1];
        v.y = MF[1][(2 * p) * 4 + i0] * MF[1][(2 * p + 1) * 4 + i1];
        PAIR2[p][e] = v;
    }
    __syncthreads();

    // ---- phase 1d: quad tables, row-interleaved (f32x2) ----
#pragma unroll
    for (int i = tid; i < 4 * 256; i += 256) {
        int g = i >> 8, e = i & 255;
        Q2[g][e] = PAIR2[2 * g][e & 15] * PAIR2[2 * g + 1][e >> 4];
    }
    __syncthreads();

    // ---- phase 2: firing-strength row sums (gather pass 1) ----
    float ssum0 = 0.0f, ssum1 = 0.0f;
#pragma unroll 1
    for (int j = 0; j < RPT; ++j) {
        unsigned int code = codes[tid + 256 * j];
        f32x2 q0 = Q2[0][code & 255u];
        f32x2 q1 = Q2[1][(code >> 8) & 255u];
        f32x2 q2 = Q2[2][(code >> 16) & 255u];
        f32x2 q3 = Q2[3][code >> 24];
        f32x2 p = (q0 * q1) * (q2 * q3);
        ssum0 += p.x;
        ssum1 += p.y;
    }

    // ---- phase 3: per-row fs total across block ----
    {
        float s0 = ssum0, s1 = ssum1;
#pragma unroll
        for (int off = 32; off > 0; off >>= 1) {
            s0 += __shfl_xor(s0, off, 64);
            s1 += __shfl_xor(s1, off, 64);
        }
        if (lane == 0) { wpart[wv][0] = s0; wpart[wv][1] = s1; }
    }
    __syncthreads();
    if (tid < TB) {
        float t = wpart[0][tid] + wpart[1][tid] + wpart[2][tid] + wpart[3][tid];
        float inv = 1.0f / (t + 1e-9f);
        invl[tid] = inv;
        oscale[tid] = sx[tid] * inv;
    }
    __syncthreads();

    const float inv0 = invl[0], inv1 = invl[1];

    // ---- phase 4: re-gather, write norm_fs, accumulate fs*Wsum ----
    float acc[TB][CC];
#pragma unroll
    for (int row = 0; row < TB; ++row)
#pragma unroll
        for (int c = 0; c < CC; ++c) acc[row][c] = 0.0f;

#pragma unroll 1
    for (int j = 0; j < RPT; ++j) {
        int r = tid + 256 * j;
        unsigned int code = codes[r];
        f32x2 q0 = Q2[0][code & 255u];
        f32x2 q1 = Q2[1][(code >> 8) & 255u];
        f32x2 q2 = Q2[2][(code >> 16) & 255u];
        f32x2 q3 = Q2[3][code >> 24];
        f32x2 p = (q0 * q1) * (q2 * q3);

        norm_fs[(size_t)(b0 + 0) * RR + r] = p.x * inv0;
        norm_fs[(size_t)(b0 + 1) * RR + r] = p.y * inv1;

        const f32x4 wa = wsum4a[r];
        const f32x4 wb = wsum4b[r];
        const f32x2 wcp = wsum2[r];
        const float wc[CC] = {wa.x, wa.y, wa.z, wa.w, wb.x,
                              wb.y, wb.z, wb.w, wcp.x, wcp.y};
#pragma unroll
        for (int c = 0; c < CC; ++c) {
            acc[0][c] = fmaf(p.x, wc[c], acc[0][c]);
            acc[1][c] = fmaf(p.y, wc[c], acc[1][c]);
        }
    }
    __syncthreads();  // Q2 reads drained -> RED aliasing safe

    // ---- phase 5: reduce acc across block ----
#pragma unroll
    for (int row = 0; row < TB; ++row) {
#pragma unroll
        for (int c = 0; c < CC; ++c) {
            float s = acc[row][c];
            s += __shfl_xor(s, 1, 64);
            s += __shfl_xor(s, 2, 64);
            if ((lane & 3) == 0) RED[row * CC + c][wv * 16 + (lane >> 2)] = s;
        }
    }
    __syncthreads();
    if (tid < 80) {
        int v = tid % 20, ch = tid / 20;   // 4 chunks of 16 columns
        float s = 0.0f;
        int base = ch * 16;
#pragma unroll
        for (int i = 0; i < 16; ++i) s += RED[v][base + i];
        part2[v][ch] = s;
    }
    __syncthreads();
    if (tid < TB * CC) {
        float val = part2[tid][0] + part2[tid][1] + part2[tid][2] + part2[tid][3];
        int row = tid / CC, c = tid % CC;
        out[(b0 + row) * CC + c] = oscale[row] * val;
    }
}

// ---------------- launch ----------------
extern "C" void kernel_launch(void* const* d_in, const int* in_sizes, int n_in,
                              void* d_out, int out_size, void* d_ws, size_t ws_size,
                              hipStream_t stream) {
    const float* x       = (const float*)d_in[0];
    const float* centers = (const float*)d_in[1];
    const float* widths  = (const float*)d_in[2];
    const float* cons    = (const float*)d_in[3];
    const int*   rules   = (const int*)d_in[4];

    float* out_p     = (float*)d_out;                       // (B, C)
    float* norm_fs_p = out_p + (size_t)BB * CC;             // (B, R)
    float* x_ext_p   = norm_fs_p + (size_t)BB * RR;         // (B, D+1)

    // workspace layout: wsum4a (32KB) | wsum4b (32KB) | wsum2 (16KB) | codes (8KB)
    float* wsum4a = (float*)d_ws;
    float* wsum4b = wsum4a + (size_t)RR * 4;
    float* wsum2  = wsum4b + (size_t)RR * 4;
    unsigned int* codes = (unsigned int*)(wsum2 + (size_t)RR * 2);

    prep_kernel<<<(RR * CC + 255) / 256, 256, 0, stream>>>(cons, rules, wsum4a,
                                                           wsum4b, wsum2, codes);
    anfis_main<<<BB / TB, 256, 0, stream>>>(x, centers, widths,
                                            (const f32x4*)wsum4a,
                                            (const f32x4*)wsum4b,
                                            (const f32x2*)wsum2, codes,
                                            out_p, norm_fs_p, x_ext_p);
}